// Round 4
// baseline (541.433 us; speedup 1.0000x reference)
//
#include <hip/hip_runtime.h>
#include <hip/hip_bf16.h>

#define NN 50000
#define NE 800000
#define DD 128
#define NCLS 40

typedef short bf8 __attribute__((ext_vector_type(8)));   // 8 bf16 (4 VGPRs)
typedef float f32x4 __attribute__((ext_vector_type(4))); // MFMA acc

__device__ __forceinline__ unsigned short f2bf(float x) {
    unsigned int u = __float_as_uint(x);
    unsigned int r = (u + 0x7FFFu + ((u >> 16) & 1u)) >> 16;  // RNE
    return (unsigned short)r;
}
__device__ __forceinline__ float bf2f(unsigned short h) {
    return __uint_as_float(((unsigned int)h) << 16);
}
// pack fp32 -> (hi bf16 <<16) | lo bf16
__device__ __forceinline__ unsigned int packhl(float v) {
    unsigned short h = f2bf(v);
    unsigned short l = f2bf(v - bf2f(h));
    return ((unsigned int)h << 16) | l;
}
// unpack to fp32 (hi + lo)
__device__ __forceinline__ float unpackhl(unsigned int p) {
    return __uint_as_float(p & 0xFFFF0000u) + __uint_as_float(p << 16);
}

// ---------------------------------------------------------------------------
__global__ void k_detect(const int* __restrict__ ei, int* __restrict__ flag) {
    __shared__ int nz;
    if (threadIdx.x == 0) nz = 0;
    __syncthreads();
    int any = 0;
    for (int e = threadIdx.x; e < 2048; e += 256)
        if (ei[2 * e + 1] != 0) any = 1;
    if (any) atomicOr(&nz, 1);
    __syncthreads();
    if (threadIdx.x == 0) *flag = (nz == 0) ? 1 : 0;  // 1 => int64 layout
}

__global__ void k_zero_int(int* __restrict__ p, int n) {
    int i = blockIdx.x * 256 + threadIdx.x;
    if (i < n) p[i] = 0;
}

__global__ void k_count(const int* __restrict__ ei, const int* __restrict__ flag,
                        int* __restrict__ cnt) {
    int e = blockIdx.x * 256 + threadIdx.x;
    if (e >= NE) return;
    int is64 = *flag;
    int d = is64 ? ei[2 * (NE + e)] : ei[NE + e];
    atomicAdd(&cnt[d], 1);
}

__global__ void k_scan1(const int* __restrict__ cnt, int* __restrict__ incl,
                        int* __restrict__ bsum) {
    __shared__ int s[1024];
    int t = threadIdx.x;
    int i = blockIdx.x * 1024 + t;
    int v = (i < NN) ? cnt[i] : 0;
    s[t] = v;
    __syncthreads();
#pragma unroll
    for (int off = 1; off < 1024; off <<= 1) {
        int u = (t >= off) ? s[t - off] : 0;
        __syncthreads();
        s[t] += u;
        __syncthreads();
    }
    if (i < NN) incl[i] = s[t];
    if (t == 1023) bsum[blockIdx.x] = s[1023];
}

__global__ void k_scan2(int* __restrict__ bsum, int* __restrict__ boff,
                        const int nb) {
    __shared__ int s[64];
    int t = threadIdx.x;
    s[t] = (t < nb) ? bsum[t] : 0;
    __syncthreads();
#pragma unroll
    for (int off = 1; off < 64; off <<= 1) {
        int u = (t >= off) ? s[t - off] : 0;
        __syncthreads();
        s[t] += u;
        __syncthreads();
    }
    if (t < nb) boff[t] = s[t] - bsum[t];
    if (t == 63) boff[nb] = s[63];
}

__global__ void k_scan3(const int* __restrict__ cnt, const int* __restrict__ incl,
                        const int* __restrict__ boff, int* __restrict__ row_ptr,
                        int* __restrict__ cursor, const int nb) {
    int i = blockIdx.x * 1024 + threadIdx.x;
    if (i < NN) {
        row_ptr[i] = incl[i] - cnt[i] + boff[blockIdx.x];
        cursor[i] = 0;
    }
    if (i == 0) row_ptr[NN] = boff[nb];
}

__global__ void k_fill(const int* __restrict__ ei, const int* __restrict__ flag,
                       const int* __restrict__ row_ptr, int* __restrict__ cursor,
                       int* __restrict__ srcs) {
    int e = blockIdx.x * 256 + threadIdx.x;
    if (e >= NE) return;
    int is64 = *flag;
    int s, d;
    if (is64) { s = ei[2 * e]; d = ei[2 * (NE + e)]; }
    else      { s = ei[e];     d = ei[NE + e]; }
    int pos = row_ptr[d] + atomicAdd(&cursor[d], 1);
    srcs[pos] = s;
}

// ---------------------------------------------------------------------------
// fp32 -> packed (hi<<16 | lo). 50000*128/4 = 1.6M float4 -> uint4.
__global__ void k_cvt_x(const float* __restrict__ x, unsigned int* __restrict__ xp) {
    int i = blockIdx.x * 256 + threadIdx.x;
    float4 v = ((const float4*)x)[i];
    uint4 o;
    o.x = packhl(v.x); o.y = packhl(v.y); o.z = packhl(v.z); o.w = packhl(v.w);
    ((uint4*)xp)[i] = o;
}

// Build Bt[n][k] (n-major, k over [Wl;Wr]), separate hi/lo, zero pad n>=NC.
__global__ void k_cvt_w(const float* __restrict__ wl, const float* __restrict__ wr,
                        unsigned short* __restrict__ bth, unsigned short* __restrict__ btl,
                        const int NC) {
    int n = blockIdx.x;
    int k = threadIdx.x;
    float v = 0.f;
    if (n < NC)
        v = (k < 128) ? wl[(size_t)k * NC + n] : wr[(size_t)(k - 128) * NC + n];
    unsigned short h = f2bf(v);
    unsigned short l = f2bf(v - bf2f(h));
    bth[(size_t)n * 256 + k] = h;
    btl[(size_t)n * 256 + k] = l;
}

// ---------------------------------------------------------------------------
// Pull-based mean aggregation on packed activations: packed in, packed out.
__global__ void k_agg(const unsigned int* __restrict__ in, const int* __restrict__ row_ptr,
                      const int* __restrict__ srcs, unsigned int* __restrict__ o) {
    int n = blockIdx.x;
    int f = threadIdx.x;  // 0..127
    int b = row_ptr[n], e = row_ptr[n + 1];
    float acc = 0.0f;
    int i = b;
    for (; i + 3 < e; i += 4) {
        int s0 = srcs[i + 0], s1 = srcs[i + 1], s2 = srcs[i + 2], s3 = srcs[i + 3];
        unsigned int p0 = in[(size_t)s0 * DD + f];
        unsigned int p1 = in[(size_t)s1 * DD + f];
        unsigned int p2 = in[(size_t)s2 * DD + f];
        unsigned int p3 = in[(size_t)s3 * DD + f];
        acc += unpackhl(p0) + unpackhl(p1) + unpackhl(p2) + unpackhl(p3);
    }
    for (; i < e; ++i) acc += unpackhl(in[(size_t)srcs[i] * DD + f]);
    int deg = e - b;
    float inv = 1.0f / (float)(deg > 0 ? deg : 1);
    o[(size_t)n * DD + f] = packhl(acc * inv);
}

// ---------------------------------------------------------------------------
// Split-precision bf16 MFMA GEMM: C = relu([A1|A2] @ Bt^T + bias)
//   A1,A2: [NN,128] packed hi/lo (K-concat: k<128 -> A1, else A2)
//   Bt:    [128,256] hi/lo bf16, n-major (zero-padded rows n>=NC)
// Wave = 1 m-tile (16 rows) x NT n-tiles; block = 4 waves = 64 rows.
// grid = (ceil(NN/64), n_halves). 3-product split: Ah*Bh + Al*Bh + Ah*Bl.
template <int NT, bool PACKOUT>
__global__ void k_mfma(const unsigned int* __restrict__ A1p, const unsigned int* __restrict__ A2p,
                       const unsigned short* __restrict__ Bth, const unsigned short* __restrict__ Btl,
                       const float* __restrict__ bias, float* __restrict__ outf,
                       unsigned int* __restrict__ outp, const int NC) {
    const int tid = threadIdx.x;
    const int wave = tid >> 6, lane = tid & 63;
    const int quad = lane >> 4, mr = lane & 15;
    const int m0 = blockIdx.x * 64 + wave * 16;
    const int n0 = blockIdx.y * (NT * 16);
    const int row = m0 + mr;
    const bool rok = row < NN;

    f32x4 acc[NT] = {};

#pragma unroll
    for (int ks = 0; ks < 8; ++ks) {
        const int kb = ks * 32;
        const unsigned int* base = (kb < 128) ? A1p : A2p;
        const int ko = (kb & 127) + quad * 8;
        uint4 p0 = make_uint4(0, 0, 0, 0), p1 = make_uint4(0, 0, 0, 0);
        if (rok) {
            const uint4* ap = (const uint4*)(base + (size_t)row * 128 + ko);
            p0 = ap[0];
            p1 = ap[1];
        }
        unsigned int u[8] = {p0.x, p0.y, p0.z, p0.w, p1.x, p1.y, p1.z, p1.w};
        bf8 ah, al;
#pragma unroll
        for (int j = 0; j < 8; ++j) {
            ah[j] = (short)(u[j] >> 16);
            al[j] = (short)(u[j] & 0xFFFFu);
        }
#pragma unroll
        for (int n = 0; n < NT; ++n) {
            size_t boff = (size_t)(n0 + n * 16 + mr) * 256 + kb + quad * 8;
            bf8 bh = *(const bf8*)(Bth + boff);
            bf8 bl = *(const bf8*)(Btl + boff);
            acc[n] = __builtin_amdgcn_mfma_f32_16x16x32_bf16(ah, bh, acc[n], 0, 0, 0);
            acc[n] = __builtin_amdgcn_mfma_f32_16x16x32_bf16(al, bh, acc[n], 0, 0, 0);
            acc[n] = __builtin_amdgcn_mfma_f32_16x16x32_bf16(ah, bl, acc[n], 0, 0, 0);
        }
    }

    // Epilogue. C/D layout: col = lane&15, row = quad*4 + reg.
#pragma unroll
    for (int n = 0; n < NT; ++n) {
        int col = n0 + n * 16 + mr;
        float bv = (col < NC) ? bias[col] : 0.f;
#pragma unroll
        for (int r = 0; r < 4; ++r) {
            int orow = m0 + quad * 4 + r;
            if (orow < NN && col < NC) {
                float v = acc[n][r] + bv;
                v = v > 0.f ? v : 0.f;
                if (PACKOUT) {
                    outp[(size_t)orow * 128 + col] = packhl(v);
                } else {
                    outf[(size_t)orow * NC + col] = v;
                }
            }
        }
    }
}

// ---------------------------------------------------------------------------
extern "C" void kernel_launch(void* const* d_in, const int* in_sizes, int n_in,
                              void* d_out, int out_size, void* d_ws, size_t ws_size,
                              hipStream_t stream) {
    const float* x    = (const float*)d_in[0];
    const int*   ei   = (const int*)d_in[1];
    const float* w1_l = (const float*)d_in[2];
    const float* w1_r = (const float*)d_in[3];
    const float* b1   = (const float*)d_in[4];
    const float* w2_l = (const float*)d_in[5];
    const float* w2_r = (const float*)d_in[6];
    const float* b2   = (const float*)d_in[7];
    const float* w3_l = (const float*)d_in[8];
    const float* w3_r = (const float*)d_in[9];
    const float* b3   = (const float*)d_in[10];
    float* out = (float*)d_out;

    char* w = (char*)d_ws;
    size_t off = 0;
    auto alloc = [&](size_t bytes) -> void* {
        void* p = w + off;
        off += (bytes + 255) / 256 * 256;
        return p;
    };
    int* flag    = (int*)alloc(4);
    int* cnt     = (int*)alloc((size_t)NN * 4);
    int* row_ptr = (int*)alloc((size_t)(NN + 1) * 4);
    int* cursor  = (int*)alloc((size_t)NN * 4);
    int* srcs    = (int*)alloc((size_t)NE * 4);
    int* incl    = (int*)alloc((size_t)NN * 4);
    int* bsum    = (int*)alloc(64 * 4);
    int* boff    = (int*)alloc(64 * 4);
    unsigned int* xp   = (unsigned int*)alloc((size_t)NN * DD * 4);  // also h2p
    unsigned int* aggp = (unsigned int*)alloc((size_t)NN * DD * 4);
    unsigned int* h1p  = (unsigned int*)alloc((size_t)NN * DD * 4);
    unsigned short* bt1h = (unsigned short*)alloc(128 * 256 * 2);
    unsigned short* bt1l = (unsigned short*)alloc(128 * 256 * 2);
    unsigned short* bt2h = (unsigned short*)alloc(128 * 256 * 2);
    unsigned short* bt2l = (unsigned short*)alloc(128 * 256 * 2);
    unsigned short* bt3h = (unsigned short*)alloc(128 * 256 * 2);
    unsigned short* bt3l = (unsigned short*)alloc(128 * 256 * 2);
    unsigned int* h2p = xp;  // x dead after layer-1 GEMM
    (void)ws_size;

    const int eb = (NE + 255) / 256;
    const int nb = (NN + 1023) / 1024;  // 49
    k_zero_int<<<(NN + 255) / 256, 256, 0, stream>>>(cnt, NN);
    k_detect<<<1, 256, 0, stream>>>(ei, flag);
    k_count<<<eb, 256, 0, stream>>>(ei, flag, cnt);
    k_scan1<<<nb, 1024, 0, stream>>>(cnt, incl, bsum);
    k_scan2<<<1, 64, 0, stream>>>(bsum, boff, nb);
    k_scan3<<<nb, 1024, 0, stream>>>(cnt, incl, boff, row_ptr, cursor, nb);
    k_fill<<<eb, 256, 0, stream>>>(ei, flag, row_ptr, cursor, srcs);

    k_cvt_x<<<(NN * DD / 4) / 256, 256, 0, stream>>>(x, xp);
    k_cvt_w<<<128, 256, 0, stream>>>(w1_l, w1_r, bt1h, bt1l, DD);
    k_cvt_w<<<128, 256, 0, stream>>>(w2_l, w2_r, bt2h, bt2l, DD);
    k_cvt_w<<<128, 256, 0, stream>>>(w3_l, w3_r, bt3h, bt3l, NCLS);

    const int gmb = (NN + 63) / 64;  // 782
    // Layer 1
    k_agg<<<NN, DD, 0, stream>>>(xp, row_ptr, srcs, aggp);
    k_mfma<4, true><<<dim3(gmb, 2), 256, 0, stream>>>(aggp, xp, bt1h, bt1l, b1,
                                                      nullptr, h1p, DD);
    // Layer 2 (h2p aliases xp; x is dead)
    k_agg<<<NN, DD, 0, stream>>>(h1p, row_ptr, srcs, aggp);
    k_mfma<4, true><<<dim3(gmb, 2), 256, 0, stream>>>(aggp, h1p, bt2h, bt2l, b2,
                                                      nullptr, h2p, DD);
    // Layer 3
    k_agg<<<NN, DD, 0, stream>>>(h2p, row_ptr, srcs, aggp);
    k_mfma<3, false><<<dim3(gmb, 1), 256, 0, stream>>>(aggp, h2p, bt3h, bt3l, b3,
                                                       out, nullptr, NCLS);
}